// Round 8
// baseline (327.177 us; speedup 1.0000x reference)
//
#include <hip/hip_runtime.h>
#include <cstdint>
#include <cstddef>

#define T_LEN 4096
#define S_DIM 308
#define E_DIM 126
#define NBATCH 32
#define CHL 16                     // chunk length: 256 chunks, ONE per block (2 blocks/CU)
#define NCH (T_LEN / CHL)          // 256
#define WARM 6                     // contraction ~0.066/step -> ~1e-6 relative after warm-up
#define NSTEP (CHL + WARM - 1)     // 21, uniform for ALL chunks (c==0 uses reset-at-IW)
#define IW (WARM - 1)              // checkpoint substep (z at t = c*CHL-1)
#define TC 8                       // emis_pack timesteps per block (1024 blocks = 4/CU)
#define ROWB 20480                 // Efrag row bytes: 40 tiles * 64 lanes * 8B
#define LN128 4.852030263919617f   // ln(128): per-step prescale to telescope out

typedef _Float16 half8 __attribute__((ext_vector_type(8)));
typedef _Float16 half4 __attribute__((ext_vector_type(4)));
typedef float floatx4 __attribute__((ext_vector_type(4)));

union HU8 { uint4 u; half8 h; };
union HU4 { uint2 u; half4 h; };
union HU1 { uint16_t u; _Float16 h; };

__device__ __forceinline__ half8 h8_from_u4(uint4 v) { HU8 t; t.u = v; return t.h; }
__device__ __forceinline__ half4 h4_from_u2(uint2 v) { HU4 t; t.u = v; return t.h; }
__device__ __forceinline__ uint32_t pk2(float x, float y) {
  HU1 a, b; a.h = (_Float16)x; b.h = (_Float16)y;
  return (uint32_t)a.u | ((uint32_t)b.u << 16);
}

// ---- merged init: blocks 0..49 pack A-frags, 50..69 pack B-frags, 70 zeroes out ----
// A-frag: tile = nt*10 + kt; lane l holds A[k=kt*32+(l>>4)*8+j][n=nt*16+(l&15)], j=0..7.
// Serves as MFMA A-operand for P^T = A^T @ Q^T (m = out-state, k = in-state).
// B-frag: tile = nt*4 + kt over E padded to 128, value = 128*B[n][k]; MFMA A-operand
// for E^T = (128*Bmat) @ inp^T in emis_pack. x128 telescopes into the loglik.
__global__ __launch_bounds__(256) void init_pack(const float* __restrict__ A,
                                                 const float* __restrict__ Bm,
                                                 uint32_t* __restrict__ Apk,
                                                 uint32_t* __restrict__ Bfr,
                                                 float* __restrict__ out) {
  int blk = blockIdx.x, tid = threadIdx.x;
  if (blk < 50) {
    int idx = blk * 256 + tid;                 // 200 tiles * 64 lanes
    int lane = idx & 63, tile = idx >> 6;
    int kt = tile % 10, nt = tile / 10;
    int n  = nt * 16 + (lane & 15);
    int k0 = kt * 32 + (lane >> 4) * 8;
    uint32_t wv[4];
#pragma unroll
    for (int jj = 0; jj < 4; jj++) {
      int ka = k0 + 2 * jj, kb = ka + 1;
      float x0 = (n < S_DIM && ka < S_DIM) ? A[ka * S_DIM + n] : 0.f;
      float x1 = (n < S_DIM && kb < S_DIM) ? A[kb * S_DIM + n] : 0.f;
      wv[jj] = pk2(x0, x1);
    }
    uint4 o; o.x = wv[0]; o.y = wv[1]; o.z = wv[2]; o.w = wv[3];
    ((uint4*)Apk)[idx] = o;
  } else if (blk < 70) {
    int idx = (blk - 50) * 256 + tid;          // 80 tiles * 64 lanes
    int lane = idx & 63, tile = idx >> 6;
    int kt = tile % 4, nt = tile / 4;
    int n  = nt * 16 + (lane & 15);
    int k0 = kt * 32 + (lane >> 4) * 8;
    uint32_t wv[4];
#pragma unroll
    for (int jj = 0; jj < 4; jj++) {
      int ka = k0 + 2 * jj, kb = ka + 1;
      float x0 = (n < S_DIM && ka < E_DIM) ? 128.f * Bm[n * E_DIM + ka] : 0.f;
      float x1 = (n < S_DIM && kb < E_DIM) ? 128.f * Bm[n * E_DIM + kb] : 0.f;
      wv[jj] = pk2(x0, x1);
    }
    uint4 o; o.x = wv[0]; o.y = wv[1]; o.z = wv[2]; o.w = wv[3];
    ((uint4*)Bfr)[idx] = o;
  } else {
    if (tid < NBATCH) out[tid] = 0.f;
  }
}

// ---- E precompute: E^T[t] fragments in main-loop register layout ----
// E^T = (128*Bmat) @ inp^T per t. Grid (T/TC, 2 batch-groups), 256 thr = 4 waves
// x 5 tiles. Lane packs its 4 f32 -> one uint2 at
// Efrag[(t*40 + bg*20 + nt)*64 + lane]  (512B fully-coalesced per wave-store).
// TC=8 -> 1024 blocks (4/CU via launch_bounds(256,4)) for latency hiding toward
// the ~22us HBM floor (140 MB traffic).
__global__ __launch_bounds__(256, 4)
void emis_pack(const uint32_t* __restrict__ Bfr, const float* __restrict__ inp,
               uint2* __restrict__ Efrag) {
  __shared__ __attribute__((aligned(16))) _Float16 inH[2][16 * 136];
  int tc = blockIdx.x, bg = blockIdx.y, bbase = bg * 16;
  int tid = threadIdx.x, lane = tid & 63, w = tid >> 6;
  int gl = lane & 15, quad = lane >> 4;

  half8 bfB[5][4];
#pragma unroll
  for (int q = 0; q < 5; q++)
#pragma unroll
    for (int kt = 0; kt < 4; kt++)
      bfB[q][kt] = h8_from_u4(((const uint4*)Bfr)[((w * 5 + q) * 4 + kt) * 64 + lane]);
#pragma unroll
  for (int q = 0; q < 5; q++)
#pragma unroll
    for (int kt = 0; kt < 4; kt++) asm volatile("" : "+v"(bfB[q][kt]));

  int t0 = tc * TC;
#pragma unroll
  for (int s = 0; s < 4; s++) {
    int flat = tid + s * 256;
    int r = flat >> 6, c2 = flat & 63;
    float2 v; v.x = 0.f; v.y = 0.f;
    if (c2 < 63) v = *(const float2*)(inp + ((size_t)(bbase + r) * T_LEN + t0) * E_DIM + 2 * c2);
    *(uint32_t*)&inH[0][r * 136 + 2 * c2] = pk2(v.x, v.y);
  }
  float2 g[4];   // prefetch t0+1
#pragma unroll
  for (int s = 0; s < 4; s++) {
    int flat = tid + s * 256;
    int r = flat >> 6, c2 = flat & 63;
    g[s].x = 0.f; g[s].y = 0.f;
    if (c2 < 63) g[s] = *(const float2*)(inp + ((size_t)(bbase + r) * T_LEN + (t0 + 1)) * E_DIM + 2 * c2);
  }
  __syncthreads();

  for (int i = 0; i < TC; i++) {
    int cur = i & 1, t = t0 + i;
    floatx4 Ea[5];
#pragma unroll
    for (int q = 0; q < 5; q++) Ea[q] = (floatx4){0.f, 0.f, 0.f, 0.f};
#pragma unroll
    for (int kt = 0; kt < 4; kt++) {
      half8 af = h8_from_u4(*(const uint4*)&inH[cur][gl * 136 + kt * 32 + quad * 8]);
#pragma unroll
      for (int q = 0; q < 5; q++)
        Ea[q] = __builtin_amdgcn_mfma_f32_16x16x32_f16(bfB[q][kt], af, Ea[q], 0, 0, 0);
    }
    if (i < TC - 1) {
#pragma unroll
      for (int s = 0; s < 4; s++) {
        int flat = tid + s * 256;
        int r = flat >> 6, c2 = flat & 63;
        uint32_t pv = (c2 < 63) ? pk2(g[s].x, g[s].y) : 0u;
        *(uint32_t*)&inH[cur ^ 1][r * 136 + 2 * c2] = pv;
      }
      int tp = t0 + i + 2; if (tp > T_LEN - 1) tp = T_LEN - 1;
#pragma unroll
      for (int s = 0; s < 4; s++) {
        int flat = tid + s * 256;
        int r = flat >> 6, c2 = flat & 63;
        g[s].x = 0.f; g[s].y = 0.f;
        if (c2 < 63) g[s] = *(const float2*)(inp + ((size_t)(bbase + r) * T_LEN + tp) * E_DIM + 2 * c2);
      }
    }
#pragma unroll
    for (int q = 0; q < 5; q++) {
      uint2 o;
      o.x = pk2(Ea[q][0], Ea[q][1]);
      o.y = pk2(Ea[q][2], Ea[q][3]);
      Efrag[((size_t)t * 40 + bg * 20 + (w * 5 + q)) * 64 + lane] = o;
    }
    __syncthreads();
  }
}

// ---- fused recursion, round-10: single-stream, 2 INDEPENDENT blocks per CU ----
// Round-7 lesson: conflict fix verified at counter level but time ~flat -> the
// pair-step is bound by the lockstep serial chain (all waves share every
// barrier; 1 block/CU leaves the CU idle during drains). Dual-stream INSIDE a
// block shares barriers (rounds 3/4: zero gain). Fix: two separate blocks per
// CU that never sync with each other -- block A's barrier drain is filled by
// block B's issue. Geometry: 256 thr = 4 waves x 5 tiles, single chunk/block,
// grid (256 chunks, 2 bg) = 512 blocks = 2/CU. Also HALVES per-step QL read
// traffic (4 waves re-read Q, not 8). launch_bounds(256,2) caps regs at the
// 2-waves/SIMD budget (bfA 200 + Pa 20 acc + ~35 misc ~= 255). Depth-1 E
// prefetch via running pointer; chunk-0 warm clamps to row 0 (re-reads E(0),
// values discarded by the exact Pa:=I reset at IW) -> no clamp VALU, no guard
// memory. QL frag-linear (round-7, verified): linear b128 reads, scatter b64
// writes, conflict-free.
__global__ __launch_bounds__(256, 2)
void hmm_fused8(const uint32_t* __restrict__ Apk, const uint2* __restrict__ Efrag,
                const float* __restrict__ Ivec, float* __restrict__ out) {
  __shared__ __attribute__((aligned(16))) _Float16 QL[2][5120];  // frag-order, dbl-buf
  __shared__ float zsl[16];
  int c = blockIdx.x, bg = blockIdx.y, bbase = bg * 16;
  int tid = threadIdx.x, lane = tid & 63, w = tid >> 6;
  int gl = lane & 15, quad = lane >> 4;

  half8 bfA[5][10];
#pragma unroll
  for (int q = 0; q < 5; q++)
#pragma unroll
    for (int kt = 0; kt < 10; kt++)
      bfA[q][kt] = h8_from_u4(((const uint4*)Apk)[((w * 5 + q) * 10 + kt) * 64 + lane]);
#pragma unroll
  for (int q = 0; q < 5; q++)
#pragma unroll
    for (int kt = 0; kt < 10; kt++) asm volatile("" : "+v"(bfA[q][kt]));

  // P state-major: lane holds states (w*5+q)*16 + quad*4 + r for batch gl
  floatx4 Pa[5];
#pragma unroll
  for (int q = 0; q < 5; q++)
#pragma unroll
    for (int r = 0; r < 4; r++) {
      int st = (w * 5 + q) * 16 + quad * 4 + r;
      Pa[q][r] = (st < S_DIM) ? ((c == 0) ? Ivec[st] : 1.0f) : 0.f;
    }
  if (tid < 16) zsl[tid] = 0.f;

  int tf = c * CHL - WARM + 1;   // -5 for c==0 (garbage warm, exact reset at IW)

  // fragment-order QL write offsets (verified round 7): nt = w*5+q
  int wboff[5];
#pragma unroll
  for (int q = 0; q < 5; q++) {
    int nt = w * 5 + q;
    int s0 = nt * 16 + quad * 4;
    wboff[q] = (s0 >> 5) * 1024 + (((((nt & 1) << 1) | (quad >> 1)) * 16 + gl) << 4)
             + ((quad & 1) << 3);
  }

  // E running pointer; row(t) clamped to 0 during chunk-0 warm (values discarded)
  size_t laneoff = ((size_t)bg * 1280 + (size_t)(w * 5) * 64 + lane) * 8;
  int r0 = tf - 1; if (r0 < 0) r0 = 0;
  const char* pE = (const char*)Efrag + (size_t)r0 * ROWB + laneoff;
  uint2 E[5];
#pragma unroll
  for (int q = 0; q < 5; q++) E[q] = *(const uint2*)(pE + q * 512);
  if (tf - 1 >= 0) pE += ROWB;

  float llw = 0.f;

  for (int ii = 0; ii <= NSTEP; ii++) {
    int cur = ii & 1;
    bool zstep = (ii == IW) || (ii == NSTEP);
    // ---- phase a: Q = P (.) E -> frag-order QL write (registers + 5 b64)
    float zacc = 0.f;
#pragma unroll
    for (int q = 0; q < 5; q++) {
      half4 ev = h4_from_u2(E[q]);
      float v0 = Pa[q][0] * (float)ev[0], v1 = Pa[q][1] * (float)ev[1];
      float v2 = Pa[q][2] * (float)ev[2], v3 = Pa[q][3] * (float)ev[3];
      if (zstep) zacc += (v0 + v1) + (v2 + v3);
      uint2 o; o.x = pk2(v0, v1); o.y = pk2(v2, v3);
      *(uint2*)((char*)&QL[cur][0] + wboff[q]) = o;
    }
    if (zstep) {
      zacc += __shfl_xor(zacc, 16);
      zacc += __shfl_xor(zacc, 32);
      if (lane < 16) atomicAdd(&zsl[lane], zacc);
    }
    __syncthreads();   // the ONLY barrier per step
    if (ii == IW && tid < 16) {
      llw = c ? logf(zsl[tid]) : 0.f;   // c==0: warm is garbage, llw stays 0
      zsl[tid] = 0.f;
    }
    if (ii == NSTEP) {
      if (tid < 16)
        atomicAdd(&out[bbase + tid], logf(zsl[tid]) - llw - (float)CHL * LN128);
      break;
    }
    // ---- phase b: depth-1 E prefetch (running ptr), then P = A^T @ Q
#pragma unroll
    for (int q = 0; q < 5; q++) E[q] = *(const uint2*)(pE + q * 512);
    if (tf + ii >= 0) pE += ROWB;      // clamp only bites during chunk-0 warm
    floatx4 a0 = (floatx4){0.f, 0.f, 0.f, 0.f};
    floatx4 a1 = a0, a2 = a0, a3 = a0, a4 = a0;
#pragma unroll
    for (int kt = 0; kt < 10; kt++) {
      half8 qf = h8_from_u4(*(const uint4*)((const char*)&QL[cur][0] + kt * 1024 + lane * 16));
      a0 = __builtin_amdgcn_mfma_f32_16x16x32_f16(bfA[0][kt], qf, a0, 0, 0, 0);
      a1 = __builtin_amdgcn_mfma_f32_16x16x32_f16(bfA[1][kt], qf, a1, 0, 0, 0);
      a2 = __builtin_amdgcn_mfma_f32_16x16x32_f16(bfA[2][kt], qf, a2, 0, 0, 0);
      a3 = __builtin_amdgcn_mfma_f32_16x16x32_f16(bfA[3][kt], qf, a3, 0, 0, 0);
      a4 = __builtin_amdgcn_mfma_f32_16x16x32_f16(bfA[4][kt], qf, a4, 0, 0, 0);
    }
    Pa[0] = a0; Pa[1] = a1; Pa[2] = a2; Pa[3] = a3; Pa[4] = a4;
    if (ii == IW && c == 0) {
      // exact restart of chunk 0 at t=0 (its next phase-a uses E(0))
#pragma unroll
      for (int q = 0; q < 5; q++)
#pragma unroll
        for (int r = 0; r < 4; r++) {
          int st = (w * 5 + q) * 16 + quad * 4 + r;
          Pa[q][r] = (st < S_DIM) ? Ivec[st] : 0.f;
        }
    }
  }
}

// ---- fallback (inp-direct, no Efrag workspace) ----
__global__ __launch_bounds__(640, 3)
void hmm_fused(const uint32_t* __restrict__ Apk,
               const uint32_t* __restrict__ Bfr,
               const float* __restrict__ inp,
               const float* __restrict__ Ivec,
               float* __restrict__ out) {
  __shared__ __attribute__((aligned(16))) _Float16 inH[2][16 * 136];
  __shared__ __attribute__((aligned(16))) _Float16 QLf[2][16 * 336];
  __shared__ float zslot[16];
  int c = blockIdx.x, bbase = blockIdx.y * 16;
  int tid = threadIdx.x, lane = tid & 63, w = tid >> 6;
  int gl = lane & 15, quad = lane >> 4;

  half8 bfA[2][10], bfB[2][4];
#pragma unroll
  for (int q = 0; q < 2; q++) {
#pragma unroll
    for (int kt = 0; kt < 10; kt++)
      bfA[q][kt] = h8_from_u4(((const uint4*)Apk)[((w * 2 + q) * 10 + kt) * 64 + lane]);
#pragma unroll
    for (int kt = 0; kt < 4; kt++)
      bfB[q][kt] = h8_from_u4(((const uint4*)Bfr)[((w * 2 + q) * 4 + kt) * 64 + lane]);
  }
#pragma unroll
  for (int q = 0; q < 2; q++) {
#pragma unroll
    for (int kt = 0; kt < 10; kt++) asm volatile("" : "+v"(bfA[q][kt]));
#pragma unroll
    for (int kt = 0; kt < 4; kt++)  asm volatile("" : "+v"(bfB[q][kt]));
  }

  float Pa[2][4];
#pragma unroll
  for (int q = 0; q < 2; q++) {
    int n = (w * 2 + q) * 16 + gl;
    float v = (n < S_DIM) ? (c == 0 ? Ivec[n] : 1.0f) : 0.f;
#pragma unroll
    for (int r = 0; r < 4; r++) Pa[q][r] = v;
  }
  if (tid < 16) zslot[tid] = 0.f;

  int t_first = (c == 0) ? 1 : (c * CHL - WARM + 1);
  int nstep   = (c == 0) ? (CHL - 1) : (CHL + WARM - 1);
  int iw      = (c == 0) ? -1 : (WARM - 1);
  int t_last  = t_first - 1 + nstep;

  {
    int t0 = t_first - 1;
#pragma unroll
    for (int s = 0; s < 2; s++) {
      int flat = tid + s * 640;
      if (flat < 1024) {
        int r = flat >> 6, c2 = flat & 63;
        float2 v; v.x = 0.f; v.y = 0.f;
        if (c2 < 63) v = *(const float2*)(inp + ((size_t)(bbase + r) * T_LEN + t0) * E_DIM + 2 * c2);
        *(uint32_t*)&inH[0][r * 136 + 2 * c2] = pk2(v.x, v.y);
      }
    }
  }
  float2 g[2];
#pragma unroll
  for (int s = 0; s < 2; s++) {
    int flat = tid + s * 640;
    g[s].x = 0.f; g[s].y = 0.f;
    if (flat < 1024) {
      int r = flat >> 6, c2 = flat & 63;
      if (c2 < 63) g[s] = *(const float2*)(inp + ((size_t)(bbase + r) * T_LEN + t_first) * E_DIM + 2 * c2);
    }
  }
  float llw = 0.f;
  __syncthreads();

  for (int i = 0; i <= nstep; i++) {
    int cur = i & 1, nxt = cur ^ 1;
    floatx4 Ea0 = (floatx4){0.f, 0.f, 0.f, 0.f};
    floatx4 Ea1 = (floatx4){0.f, 0.f, 0.f, 0.f};
#pragma unroll
    for (int kt = 0; kt < 4; kt++) {
      half8 af = h8_from_u4(*(const uint4*)&inH[cur][gl * 136 + kt * 32 + quad * 8]);
      Ea0 = __builtin_amdgcn_mfma_f32_16x16x32_f16(af, bfB[0][kt], Ea0, 0, 0, 0);
      Ea1 = __builtin_amdgcn_mfma_f32_16x16x32_f16(af, bfB[1][kt], Ea1, 0, 0, 0);
    }
    float qv[2][4];
#pragma unroll
    for (int r = 0; r < 4; r++) { qv[0][r] = Pa[0][r] * Ea0[r]; qv[1][r] = Pa[1][r] * Ea1[r]; }
    if (i == iw || i == nstep) {
      float s0 = qv[0][0] + qv[1][0], s1 = qv[0][1] + qv[1][1];
      float s2 = qv[0][2] + qv[1][2], s3 = qv[0][3] + qv[1][3];
#pragma unroll
      for (int off = 1; off <= 8; off <<= 1) {
        s0 += __shfl_xor(s0, off); s1 += __shfl_xor(s1, off);
        s2 += __shfl_xor(s2, off); s3 += __shfl_xor(s3, off);
      }
      if (gl == 0) {
        atomicAdd(&zslot[quad * 4 + 0], s0);
        atomicAdd(&zslot[quad * 4 + 1], s1);
        atomicAdd(&zslot[quad * 4 + 2], s2);
        atomicAdd(&zslot[quad * 4 + 3], s3);
      }
    }
#pragma unroll
    for (int q = 0; q < 2; q++) {
      int k = (w * 2 + q) * 16 + gl;
#pragma unroll
      for (int r = 0; r < 4; r++)
        QLf[cur][(quad * 4 + r) * 336 + k] = (_Float16)qv[q][r];
    }
    if (i < nstep) {
#pragma unroll
      for (int s = 0; s < 2; s++) {
        int flat = tid + s * 640;
        if (flat < 1024) {
          int r = flat >> 6, c2 = flat & 63;
          uint32_t pv = (c2 < 63) ? pk2(g[s].x, g[s].y) : 0u;
          *(uint32_t*)&inH[nxt][r * 136 + 2 * c2] = pv;
        }
      }
    }
    __syncthreads();
    if (i == iw && tid < 16) { llw = logf(zslot[tid]); zslot[tid] = 0.f; }
    if (i == nstep) {
      if (tid < 16) {
        float lle = logf(zslot[tid]);
        atomicAdd(&out[bbase + tid], lle - llw - (float)CHL * LN128);
      }
      break;
    }
    {
      int tp = t_first + i + 1; if (tp > t_last) tp = t_last;
#pragma unroll
      for (int s = 0; s < 2; s++) {
        int flat = tid + s * 640;
        g[s].x = 0.f; g[s].y = 0.f;
        if (flat < 1024) {
          int r = flat >> 6, c2 = flat & 63;
          if (c2 < 63) g[s] = *(const float2*)(inp + ((size_t)(bbase + r) * T_LEN + tp) * E_DIM + 2 * c2);
        }
      }
    }
    floatx4 acc0 = (floatx4){0.f, 0.f, 0.f, 0.f};
    floatx4 acc1 = (floatx4){0.f, 0.f, 0.f, 0.f};
#pragma unroll
    for (int kt = 0; kt < 10; kt++) {
      half8 afv = h8_from_u4(*(const uint4*)&QLf[cur][gl * 336 + kt * 32 + quad * 8]);
      acc0 = __builtin_amdgcn_mfma_f32_16x16x32_f16(afv, bfA[0][kt], acc0, 0, 0, 0);
      acc1 = __builtin_amdgcn_mfma_f32_16x16x32_f16(afv, bfA[1][kt], acc1, 0, 0, 0);
    }
#pragma unroll
    for (int r = 0; r < 4; r++) { Pa[0][r] = acc0[r]; Pa[1][r] = acc1[r]; }
  }
}

extern "C" void kernel_launch(void* const* d_in, const int* in_sizes, int n_in,
                              void* d_out, int out_size, void* d_ws, size_t ws_size,
                              hipStream_t stream) {
  const float* inp = (const float*)d_in[0];   // [32,4096,126]
  const float* A   = (const float*)d_in[1];   // [308,308]
  const float* Bm  = (const float*)d_in[2];   // [308,126]
  const float* Iv  = (const float*)d_in[3];   // [308]
  float* out = (float*)d_out;                 // [32]

  uint8_t* ws = (uint8_t*)d_ws;
  uint32_t* Apk = (uint32_t*)(ws);                 // 200 KiB
  uint32_t* Bfr = (uint32_t*)(ws + (256u << 10));  // 80 KiB
  const size_t EOFF   = (size_t)384 << 10;
  const size_t EBYTES = (size_t)T_LEN * ROWB;      // 80 MiB (rows t = 0..4095)

  hipLaunchKernelGGL(init_pack, dim3(71), dim3(256), 0, stream, A, Bm, Apk, Bfr, out);
  if (ws_size >= EOFF + EBYTES) {
    uint2* Efrag = (uint2*)(ws + EOFF);
    hipLaunchKernelGGL(emis_pack, dim3(T_LEN / TC, 2), dim3(256), 0, stream, Bfr, inp, Efrag);
    hipLaunchKernelGGL(hmm_fused8, dim3(NCH, NBATCH / 16), dim3(256), 0, stream,
                       Apk, Efrag, Iv, out);
  } else {
    hipLaunchKernelGGL(hmm_fused, dim3(NCH, NBATCH / 16), dim3(640), 0, stream,
                       Apk, Bfr, inp, Iv, out);
  }
}